// Round 11
// baseline (624.361 us; speedup 1.0000x reference)
//
#include <hip/hip_runtime.h>
#include <hip/hip_bf16.h>

#define NN 50000   // nodes
#define NE 800000  // edges
#define NG 256     // graphs
#define CIN 128
#define CH 256

typedef unsigned short u16;
typedef unsigned int u32;
typedef __attribute__((ext_vector_type(8))) short short8;            // 8 bf16 = 4 VGPRs
typedef __attribute__((ext_vector_type(8))) unsigned short ushort8;
typedef __attribute__((ext_vector_type(4))) float f32x4;

__device__ __forceinline__ float bf2f(u16 u) { return __uint_as_float(((u32)u) << 16); }
__device__ __forceinline__ u16 f2bf(float f) {
    u32 u = __float_as_uint(f);
    return (u16)((u + 0x7fffu + ((u >> 16) & 1u)) >> 16);  // RNE
}

// ---------------- init: zero deg/fill + pool ranges ----------------
__global__ void k_init(int* __restrict__ deg_fill, int* __restrict__ gs, int* __restrict__ ge) {
    int i = blockIdx.x * 256 + threadIdx.x;
    if (i < 2 * NN) deg_fill[i] = 0;
    if (i < NG) { gs[i] = 0; ge[i] = 0; }
}

// ---------------- CSR degree count + (merged) pool bounds ----------------
__global__ void k_count_deg_bounds(const int* __restrict__ dst, int* __restrict__ deg,
                                   const int* __restrict__ batch,
                                   int* __restrict__ gs, int* __restrict__ ge) {
    int e = blockIdx.x * 256 + threadIdx.x;
    if (e < NE) atomicAdd(&deg[dst[e]], 1);
    if (e < NN) {  // batch is sorted: boundary detection, no atomics
        int b = batch[e];
        if (e == 0 || batch[e - 1] != b) gs[b] = e;
        if (e == NN - 1 || batch[e + 1] != b) ge[b] = e + 1;
    }
}

__global__ void k_scan1(const int* __restrict__ deg, int* __restrict__ bsum) {
    __shared__ int sd[256];
    int base = blockIdx.x * 1024, t = threadIdx.x, s = 0;
    for (int j = 0; j < 4; j++) { int i = base + t * 4 + j; if (i < NN) s += deg[i]; }
    sd[t] = s; __syncthreads();
    for (int off = 128; off > 0; off >>= 1) { if (t < off) sd[t] += sd[t + off]; __syncthreads(); }
    if (t == 0) bsum[blockIdx.x] = sd[0];
}

// single-wave shuffle scan over nb<=64 block sums
__global__ void k_scan2(int* bsum, int nb, int* row_ptr) {
    int lane = threadIdx.x;
    int v = (lane < nb) ? bsum[lane] : 0;
    int s = v;
    for (int off = 1; off < 64; off <<= 1) {
        int t = __shfl_up(s, off, 64);
        if (lane >= off) s += t;
    }
    if (lane < nb) bsum[lane] = s - v;  // exclusive prefix
    if (lane == 0) row_ptr[NN] = NE;
}

__global__ void k_scan3(const int* __restrict__ deg, const int* __restrict__ bsum,
                        int* __restrict__ row_ptr) {
    __shared__ int sd[256];
    int base = blockIdx.x * 1024, t = threadIdx.x;
    int v[4]; int s = 0;
    for (int j = 0; j < 4; j++) { int i = base + t * 4 + j; v[j] = (i < NN) ? deg[i] : 0; s += v[j]; }
    sd[t] = s; __syncthreads();
    for (int off = 1; off < 256; off <<= 1) {
        int tmp = (t >= off) ? sd[t - off] : 0; __syncthreads();
        sd[t] += tmp; __syncthreads();
    }
    int run = bsum[blockIdx.x] + sd[t] - s;
    for (int j = 0; j < 4; j++) { int i = base + t * 4 + j; if (i < NN) row_ptr[i] = run; run += v[j]; }
}

__global__ void k_fill(const int* __restrict__ src, const int* __restrict__ dst,
                       const int* __restrict__ row_ptr, int* __restrict__ fill,
                       int* __restrict__ col) {
    int e = blockIdx.x * 256 + threadIdx.x;
    if (e < NE) {
        int d = dst[e];
        int pos = row_ptr[d] + atomicAdd(&fill[d], 1);
        col[pos] = src[e];
    }
}

// ---------------- prep: x fp32->bf16 + all weight packs, one dispatch -------
// Wp arena order: w1_0(128x256) | w2_0 | w1s[0..2] | w2s[0..2]  (CHxCH each)
__global__ void k_prep(const float* __restrict__ x, u16* __restrict__ xb,
                       const float* __restrict__ w1_0, const float* __restrict__ w2_0,
                       const float* __restrict__ w1s, const float* __restrict__ w2s,
                       u16* __restrict__ Wp) {
    int t = blockIdx.x * 256 + threadIdx.x;
    if (t < NN * CIN / 4) {
        float4 v = ((const float4*)x)[t];
        ushort4 o; o.x = f2bf(v.x); o.y = f2bf(v.y); o.z = f2bf(v.z); o.w = f2bf(v.w);
        ((ushort4*)xb)[t] = o;
    }
    if (t < CIN * CH + 7 * CH * CH) {
        const float* Wsrc; int rem;
        if (t < CIN * CH) { Wsrc = w1_0; rem = t; }
        else {
            int o = t - CIN * CH;
            int m = o >> 16; rem = o & 65535;  // CH*CH = 65536
            Wsrc = (m == 0) ? w2_0
                 : (m <= 3) ? w1s + (size_t)(m - 1) * 65536
                            : w2s + (size_t)(m - 4) * 65536;
        }
        // Wp[o]: o = ((kb*16+nt)*64+lane)*8+j  <-  W[kb*32+(lane>>4)*8+j][nt*16+(lane&15)]
        int j = rem & 7, lane = (rem >> 3) & 63, nt = (rem >> 9) & 15, kb = rem >> 13;
        int k = kb * 32 + ((lane >> 4) << 3) + j;
        int nc = nt * 16 + (lane & 15);
        Wp[t] = f2bf(Wsrc[k * CH + nc]);
    }
}

// ---------------- fused GIN layer -------------------------------------------
// out = relu(relu((G[i] + sum_nbr G) @ W1 + b1) @ W2 + b2), 64-node tile.
// Phase 1: cooperative gather+sum -> LDS zs (bf16). Phase 2: GEMM1 a from LDS,
// W1-frags global (1-deep prefetch). Phase 3: z1 reuses zs. Phase 4: GEMM2.
// Phase 5: epilogue via LDS -> coalesced dwordx4 stores (8 x uint4 per thread
// — r10 bug was storing only 4 and leaving half of every row unwritten).
#define ZS 264   // LDS row stride (u16); 528B = 33*16B -> 16B-aligned frags
template <int K1>
__global__ __launch_bounds__(256) void k_layer(const u16* __restrict__ G,
                                               const int* __restrict__ row_ptr,
                                               const int* __restrict__ col,
                                               const u16* __restrict__ Wp1,
                                               const float* __restrict__ b1,
                                               const u16* __restrict__ Wp2,
                                               const float* __restrict__ b2,
                                               u16* __restrict__ out) {
    __shared__ __align__(16) u16 zs[64 * ZS];  // 33.8 KB
    const int tid = threadIdx.x;
    const int wave = tid >> 6, lane = tid & 63;
    const int quad = lane >> 4, l16 = lane & 15;
    const int m0 = blockIdx.x * 64;

    // ---- phase 1: gather+sum into zs ----
    constexpr int LPR = K1 / 8;     // lanes covering one row (16B/lane)
    constexpr int RPG = 64 / LPR;   // rows gathered in parallel per wave
    const int sub = lane / LPR;
    const int c0 = (lane % LPR) * 8;
    for (int g = 0; g < 16; g += RPG) {
        int lr = wave * 16 + g + sub;
        int r = m0 + lr; if (r >= NN) r = NN - 1;
        const u16* base = G + c0;
        float a[8];
        ushort8 sv = *(const ushort8*)(base + (size_t)r * K1);
#pragma unroll
        for (int i = 0; i < 8; i++) a[i] = bf2f(sv[i]);
        int beg = row_ptr[r], end = row_ptr[r + 1];
        int e = beg;
        for (; e + 4 <= end; e += 4) {
            ushort8 v0 = *(const ushort8*)(base + (size_t)col[e] * K1);
            ushort8 v1 = *(const ushort8*)(base + (size_t)col[e + 1] * K1);
            ushort8 v2 = *(const ushort8*)(base + (size_t)col[e + 2] * K1);
            ushort8 v3 = *(const ushort8*)(base + (size_t)col[e + 3] * K1);
#pragma unroll
            for (int i = 0; i < 8; i++)
                a[i] += bf2f(v0[i]) + bf2f(v1[i]) + bf2f(v2[i]) + bf2f(v3[i]);
        }
        for (; e < end; e++) {
            ushort8 nv = *(const ushort8*)(base + (size_t)col[e] * K1);
#pragma unroll
            for (int i = 0; i < 8; i++) a[i] += bf2f(nv[i]);
        }
        ushort8 o;
#pragma unroll
        for (int i = 0; i < 8; i++) o[i] = f2bf(a[i]);
        *(ushort8*)(zs + lr * ZS + c0) = o;
    }
    __syncthreads();

    // ---- phase 2: GEMM1 (a from LDS, b from global, 1-deep prefetch) ----
    f32x4 acc[4][4];
#pragma unroll
    for (int ri = 0; ri < 4; ri++)
#pragma unroll
        for (int nj = 0; nj < 4; nj++) acc[ri][nj] = (f32x4){0.f, 0.f, 0.f, 0.f};

    const u16* w1b = Wp1 + (wave * 4) * 512 + lane * 8;
    const u16* w2b = Wp2 + (wave * 4) * 512 + lane * 8;
    constexpr int KB1 = K1 / 32;
    short8 b_cur[4], b_nxt[4];
#pragma unroll
    for (int nj = 0; nj < 4; nj++) b_cur[nj] = *(const short8*)(w1b + nj * 512);

#pragma unroll
    for (int kb = 0; kb < KB1; kb++) {
        int kn = (kb + 1 < KB1) ? (kb + 1) : kb;
#pragma unroll
        for (int nj = 0; nj < 4; nj++)
            b_nxt[nj] = *(const short8*)(w1b + kn * 8192 + nj * 512);
        short8 a[4];
#pragma unroll
        for (int ri = 0; ri < 4; ri++)
            a[ri] = *(const short8*)(zs + (ri * 16 + l16) * ZS + kb * 32 + quad * 8);
#pragma unroll
        for (int nj = 0; nj < 4; nj++)
#pragma unroll
            for (int ri = 0; ri < 4; ri++)
                acc[ri][nj] = __builtin_amdgcn_mfma_f32_16x16x32_bf16(a[ri], b_cur[nj], acc[ri][nj], 0, 0, 0);
#pragma unroll
        for (int nj = 0; nj < 4; nj++) b_cur[nj] = b_nxt[nj];
    }
    __syncthreads();  // all zs reads complete before overwrite

    // ---- phase 3: bias1 + relu -> zs ----
#pragma unroll
    for (int nj = 0; nj < 4; nj++) {
        int cc = wave * 64 + nj * 16 + l16;
        float bv = b1[cc];
#pragma unroll
        for (int ri = 0; ri < 4; ri++) {
            f32x4 v = acc[ri][nj];
#pragma unroll
            for (int j = 0; j < 4; j++)
                zs[(ri * 16 + quad * 4 + j) * ZS + cc] = f2bf(fmaxf(v[j] + bv, 0.f));
        }
    }
    __syncthreads();

    // ---- phase 4: GEMM2 (K=256) ----
#pragma unroll
    for (int ri = 0; ri < 4; ri++)
#pragma unroll
        for (int nj = 0; nj < 4; nj++) acc[ri][nj] = (f32x4){0.f, 0.f, 0.f, 0.f};
#pragma unroll
    for (int nj = 0; nj < 4; nj++) b_cur[nj] = *(const short8*)(w2b + nj * 512);

#pragma unroll
    for (int kb = 0; kb < 8; kb++) {
        int kn = (kb + 1 < 8) ? (kb + 1) : kb;
#pragma unroll
        for (int nj = 0; nj < 4; nj++)
            b_nxt[nj] = *(const short8*)(w2b + kn * 8192 + nj * 512);
        short8 a[4];
#pragma unroll
        for (int ri = 0; ri < 4; ri++)
            a[ri] = *(const short8*)(zs + (ri * 16 + l16) * ZS + kb * 32 + quad * 8);
#pragma unroll
        for (int nj = 0; nj < 4; nj++)
#pragma unroll
            for (int ri = 0; ri < 4; ri++)
                acc[ri][nj] = __builtin_amdgcn_mfma_f32_16x16x32_bf16(a[ri], b_cur[nj], acc[ri][nj], 0, 0, 0);
#pragma unroll
        for (int nj = 0; nj < 4; nj++) b_cur[nj] = b_nxt[nj];
    }
    __syncthreads();  // zs reads done before overwrite

    // ---- phase 5: bias2 + relu -> zs, coalesced stores ----
#pragma unroll
    for (int nj = 0; nj < 4; nj++) {
        int cc = wave * 64 + nj * 16 + l16;
        float bv = b2[cc];
#pragma unroll
        for (int ri = 0; ri < 4; ri++) {
            f32x4 v = acc[ri][nj];
#pragma unroll
            for (int j = 0; j < 4; j++)
                zs[(ri * 16 + quad * 4 + j) * ZS + cc] = f2bf(fmaxf(v[j] + bv, 0.f));
        }
    }
    __syncthreads();

    // 64 rows x 512 B; each thread stores 64 u16 = 8 x uint4 (full row chunk)
    int row = tid >> 2, cb = (tid & 3) * 64;
    if (m0 + row < NN) {
        uint4* dst = (uint4*)(out + (size_t)(m0 + row) * CH + cb);
        const u16* srcp = zs + row * ZS + cb;
#pragma unroll
        for (int c = 0; c < 8; c++) dst[c] = *(const uint4*)(srcp + c * 8);
    }
}

// ---------------- global_add_pool ----------------
__global__ void k_pool(const u16* __restrict__ h, const int* __restrict__ gs,
                       const int* __restrict__ ge, float* __restrict__ out) {
    int g = blockIdx.x, c = threadIdx.x;
    int s = gs[g], e = ge[g];
    float acc = 0.f;
    for (int i = s; i < e; i++) acc += bf2f(h[(size_t)i * CH + c]);
    out[g * CH + c] = acc;
}

extern "C" void kernel_launch(void* const* d_in, const int* in_sizes, int n_in,
                              void* d_out, int out_size, void* d_ws, size_t ws_size,
                              hipStream_t stream) {
    const float* x     = (const float*)d_in[0];
    const int*   ei    = (const int*)d_in[1];
    const int*   batch = (const int*)d_in[2];
    const float* w1_0  = (const float*)d_in[3];
    const float* b1_0  = (const float*)d_in[4];
    const float* w2_0  = (const float*)d_in[5];
    const float* b2_0  = (const float*)d_in[6];
    const float* w1s   = (const float*)d_in[7];
    const float* b1s   = (const float*)d_in[8];
    const float* w2s   = (const float*)d_in[9];
    const float* b2s   = (const float*)d_in[10];
    float* out = (float*)d_out;

    char* p = (char*)d_ws;
    u16* Hb  = (u16*)p; p += (size_t)NN * CH * 2;
    u16* Tb  = (u16*)p; p += (size_t)NN * CH * 2;
    u16* xb  = (u16*)p; p += (size_t)NN * CIN * 2;
    u16* WpA = (u16*)p; p += (size_t)(CIN * CH + 7 * CH * CH) * 2;  // 1+7 packed mats
    int* row_ptr = (int*)p; p += (size_t)(NN + 1) * 4;
    int* deg  = (int*)p; p += (size_t)NN * 4;
    int* fill = (int*)p; p += (size_t)NN * 4;   // adjacent to deg (zeroed together)
    int* col  = (int*)p; p += (size_t)NE * 4;
    int* bsum = (int*)p; p += 64 * 4;
    int* gs   = (int*)p; p += NG * 4;
    int* ge   = (int*)p; p += NG * 4;

    u16* Wp1_0 = WpA;                          // 128x256
    u16* Wp2_0 = Wp1_0 + CIN * CH;             // 256x256
    u16* Wp1sA = Wp2_0 + CH * CH;              // 3 x 256x256
    u16* Wp2sA = Wp1sA + 3 * CH * CH;          // 3 x 256x256

    const int* srcv = ei;
    const int* dstv = ei + NE;

    int nb = (NN + 1023) / 1024;  // 49
    hipLaunchKernelGGL(k_init, dim3((2 * NN + 255) / 256), dim3(256), 0, stream, deg, gs, ge);
    hipLaunchKernelGGL(k_count_deg_bounds, dim3((NE + 255) / 256), dim3(256), 0, stream,
                       dstv, deg, batch, gs, ge);
    hipLaunchKernelGGL(k_scan1, dim3(nb), dim3(256), 0, stream, deg, bsum);
    hipLaunchKernelGGL(k_scan2, dim3(1), dim3(64), 0, stream, bsum, nb, row_ptr);
    hipLaunchKernelGGL(k_scan3, dim3(nb), dim3(256), 0, stream, deg, bsum, row_ptr);
    hipLaunchKernelGGL(k_fill, dim3((NE + 255) / 256), dim3(256), 0, stream, srcv, dstv, row_ptr, fill, col);
    hipLaunchKernelGGL(k_prep, dim3((NN * CIN / 4 + 255) / 256), dim3(256), 0, stream,
                       x, xb, w1_0, w2_0, w1s, w2s, WpA);

    int layerBlocks = (NN + 63) / 64;  // 782

    // layer 0: xb -> Hb; layers 1..3 ping-pong (gather src != store dst)
    hipLaunchKernelGGL((k_layer<128>), dim3(layerBlocks), dim3(256), 0, stream,
                       xb, row_ptr, col, Wp1_0, b1_0, Wp2_0, b2_0, Hb);
    hipLaunchKernelGGL((k_layer<256>), dim3(layerBlocks), dim3(256), 0, stream,
                       Hb, row_ptr, col, Wp1sA, b1s, Wp2sA, b2s, Tb);
    hipLaunchKernelGGL((k_layer<256>), dim3(layerBlocks), dim3(256), 0, stream,
                       Tb, row_ptr, col, Wp1sA + (size_t)CH * CH, b1s + CH,
                       Wp2sA + (size_t)CH * CH, b2s + CH, Hb);
    hipLaunchKernelGGL((k_layer<256>), dim3(layerBlocks), dim3(256), 0, stream,
                       Hb, row_ptr, col, Wp1sA + (size_t)2 * CH * CH, b1s + 2 * CH,
                       Wp2sA + (size_t)2 * CH * CH, b2s + 2 * CH, Tb);

    hipLaunchKernelGGL(k_pool, dim3(NG), dim3(256), 0, stream, Tb, gs, ge, out);
}

// Round 12
// 588.642 us; speedup vs baseline: 1.0607x; 1.0607x over previous
//
#include <hip/hip_runtime.h>
#include <hip/hip_bf16.h>

#define NN 50000   // nodes
#define NE 800000  // edges
#define NG 256     // graphs
#define CIN 128
#define CH 256

typedef unsigned short u16;
typedef unsigned int u32;
typedef __attribute__((ext_vector_type(8))) short short8;            // 8 bf16 = 4 VGPRs
typedef __attribute__((ext_vector_type(8))) unsigned short ushort8;
typedef __attribute__((ext_vector_type(4))) float f32x4;

__device__ __forceinline__ float bf2f(u16 u) { return __uint_as_float(((u32)u) << 16); }
__device__ __forceinline__ u16 f2bf(float f) {
    u32 u = __float_as_uint(f);
    return (u16)((u + 0x7fffu + ((u >> 16) & 1u)) >> 16);  // RNE
}

// ---------------- init: zero deg/fill + pool ranges ----------------
__global__ void k_init(int* __restrict__ deg_fill, int* __restrict__ gs, int* __restrict__ ge) {
    int i = blockIdx.x * 256 + threadIdx.x;
    if (i < 2 * NN) deg_fill[i] = 0;
    if (i < NG) { gs[i] = 0; ge[i] = 0; }
}

// ---------------- CSR degree count + (merged) pool bounds ----------------
__global__ void k_count_deg_bounds(const int* __restrict__ dst, int* __restrict__ deg,
                                   const int* __restrict__ batch,
                                   int* __restrict__ gs, int* __restrict__ ge) {
    int e = blockIdx.x * 256 + threadIdx.x;
    if (e < NE) atomicAdd(&deg[dst[e]], 1);
    if (e < NN) {  // batch is sorted: boundary detection, no atomics
        int b = batch[e];
        if (e == 0 || batch[e - 1] != b) gs[b] = e;
        if (e == NN - 1 || batch[e + 1] != b) ge[b] = e + 1;
    }
}

__global__ void k_scan1(const int* __restrict__ deg, int* __restrict__ bsum) {
    __shared__ int sd[256];
    int base = blockIdx.x * 1024, t = threadIdx.x, s = 0;
    for (int j = 0; j < 4; j++) { int i = base + t * 4 + j; if (i < NN) s += deg[i]; }
    sd[t] = s; __syncthreads();
    for (int off = 128; off > 0; off >>= 1) { if (t < off) sd[t] += sd[t + off]; __syncthreads(); }
    if (t == 0) bsum[blockIdx.x] = sd[0];
}

// single-wave shuffle scan over nb<=64 block sums
__global__ void k_scan2(int* bsum, int nb, int* row_ptr) {
    int lane = threadIdx.x;
    int v = (lane < nb) ? bsum[lane] : 0;
    int s = v;
    for (int off = 1; off < 64; off <<= 1) {
        int t = __shfl_up(s, off, 64);
        if (lane >= off) s += t;
    }
    if (lane < nb) bsum[lane] = s - v;  // exclusive prefix
    if (lane == 0) row_ptr[NN] = NE;
}

__global__ void k_scan3(const int* __restrict__ deg, const int* __restrict__ bsum,
                        int* __restrict__ row_ptr) {
    __shared__ int sd[256];
    int base = blockIdx.x * 1024, t = threadIdx.x;
    int v[4]; int s = 0;
    for (int j = 0; j < 4; j++) { int i = base + t * 4 + j; v[j] = (i < NN) ? deg[i] : 0; s += v[j]; }
    sd[t] = s; __syncthreads();
    for (int off = 1; off < 256; off <<= 1) {
        int tmp = (t >= off) ? sd[t - off] : 0; __syncthreads();
        sd[t] += tmp; __syncthreads();
    }
    int run = bsum[blockIdx.x] + sd[t] - s;
    for (int j = 0; j < 4; j++) { int i = base + t * 4 + j; if (i < NN) row_ptr[i] = run; run += v[j]; }
}

__global__ void k_fill(const int* __restrict__ src, const int* __restrict__ dst,
                       const int* __restrict__ row_ptr, int* __restrict__ fill,
                       int* __restrict__ col) {
    int e = blockIdx.x * 256 + threadIdx.x;
    if (e < NE) {
        int d = dst[e];
        int pos = row_ptr[d] + atomicAdd(&fill[d], 1);
        col[pos] = src[e];
    }
}

// ---------------- prep: x fp32->bf16 + all weight packs, one dispatch -------
// Wp arena order: w1_0(128x256) | w2_0 | w1s[0..2] | w2s[0..2]  (CHxCH each)
__global__ void k_prep(const float* __restrict__ x, u16* __restrict__ xb,
                       const float* __restrict__ w1_0, const float* __restrict__ w2_0,
                       const float* __restrict__ w1s, const float* __restrict__ w2s,
                       u16* __restrict__ Wp) {
    int t = blockIdx.x * 256 + threadIdx.x;
    if (t < NN * CIN / 4) {
        float4 v = ((const float4*)x)[t];
        ushort4 o; o.x = f2bf(v.x); o.y = f2bf(v.y); o.z = f2bf(v.z); o.w = f2bf(v.w);
        ((ushort4*)xb)[t] = o;
    }
    if (t < CIN * CH + 7 * CH * CH) {
        const float* Wsrc; int rem;
        if (t < CIN * CH) { Wsrc = w1_0; rem = t; }
        else {
            int o = t - CIN * CH;
            int m = o >> 16; rem = o & 65535;  // CH*CH = 65536
            Wsrc = (m == 0) ? w2_0
                 : (m <= 3) ? w1s + (size_t)(m - 1) * 65536
                            : w2s + (size_t)(m - 4) * 65536;
        }
        // Wp[o]: o = ((kb*16+nt)*64+lane)*8+j  <-  W[kb*32+(lane>>4)*8+j][nt*16+(lane&15)]
        int j = rem & 7, lane = (rem >> 3) & 63, nt = (rem >> 9) & 15, kb = rem >> 13;
        int k = kb * 32 + ((lane >> 4) << 3) + j;
        int nc = nt * 16 + (lane & 15);
        Wp[t] = f2bf(Wsrc[k * CH + nc]);
    }
}

// ---------------- fused GIN layer (32-row tile) ------------------------------
// out = relu(relu((G[i] + sum_nbr G) @ W1 + b1) @ W2 + b2).
// r11 post-mortem: 64-row tile -> 782 blocks = 3/CU, occupancy 19.7%, no
// cross-block phase overlap. 32-row tile -> 1563 blocks (6.1/CU), 16.9 KB LDS,
// VGPR ~80 -> ~6 blocks resident/CU at staggered phases: some gather (VMEM)
// while others GEMM (MFMA).
#define ZS 264   // LDS row stride (u16); 528B -> 16B-aligned frags
template <int K1>
__global__ __launch_bounds__(256) void k_layer(const u16* __restrict__ G,
                                               const int* __restrict__ row_ptr,
                                               const int* __restrict__ col,
                                               const u16* __restrict__ Wp1,
                                               const float* __restrict__ b1,
                                               const u16* __restrict__ Wp2,
                                               const float* __restrict__ b2,
                                               u16* __restrict__ out) {
    __shared__ __align__(16) u16 zs[32 * ZS];  // 16.9 KB
    const int tid = threadIdx.x;
    const int wave = tid >> 6, lane = tid & 63;
    const int quad = lane >> 4, l16 = lane & 15;
    const int m0 = blockIdx.x * 32;

    // ---- phase 1: gather+sum into zs (16B/lane) ----
    constexpr int LPR = K1 / 8;     // lanes covering one row
    constexpr int RPG = 64 / LPR;   // rows gathered in parallel per wave
    const int sub = lane / LPR;
    const int c0 = (lane % LPR) * 8;
    for (int g = 0; g < 8; g += RPG) {
        int lr = wave * 8 + g + sub;
        int r = m0 + lr; if (r >= NN) r = NN - 1;
        const u16* base = G + c0;
        float a[8];
        ushort8 sv = *(const ushort8*)(base + (size_t)r * K1);
#pragma unroll
        for (int i = 0; i < 8; i++) a[i] = bf2f(sv[i]);
        int beg = row_ptr[r], end = row_ptr[r + 1];
        int e = beg;
        for (; e + 4 <= end; e += 4) {
            ushort8 v0 = *(const ushort8*)(base + (size_t)col[e] * K1);
            ushort8 v1 = *(const ushort8*)(base + (size_t)col[e + 1] * K1);
            ushort8 v2 = *(const ushort8*)(base + (size_t)col[e + 2] * K1);
            ushort8 v3 = *(const ushort8*)(base + (size_t)col[e + 3] * K1);
#pragma unroll
            for (int i = 0; i < 8; i++)
                a[i] += bf2f(v0[i]) + bf2f(v1[i]) + bf2f(v2[i]) + bf2f(v3[i]);
        }
        for (; e < end; e++) {
            ushort8 nv = *(const ushort8*)(base + (size_t)col[e] * K1);
#pragma unroll
            for (int i = 0; i < 8; i++) a[i] += bf2f(nv[i]);
        }
        ushort8 o;
#pragma unroll
        for (int i = 0; i < 8; i++) o[i] = f2bf(a[i]);
        *(ushort8*)(zs + lr * ZS + c0) = o;
    }
    __syncthreads();

    // ---- phase 2: GEMM1 (a from LDS, b from global, 1-deep prefetch) ----
    f32x4 acc[2][4];
#pragma unroll
    for (int ri = 0; ri < 2; ri++)
#pragma unroll
        for (int nj = 0; nj < 4; nj++) acc[ri][nj] = (f32x4){0.f, 0.f, 0.f, 0.f};

    const u16* w1b = Wp1 + (wave * 4) * 512 + lane * 8;
    const u16* w2b = Wp2 + (wave * 4) * 512 + lane * 8;
    constexpr int KB1 = K1 / 32;
    short8 b_cur[4], b_nxt[4];
#pragma unroll
    for (int nj = 0; nj < 4; nj++) b_cur[nj] = *(const short8*)(w1b + nj * 512);

#pragma unroll
    for (int kb = 0; kb < KB1; kb++) {
        int kn = (kb + 1 < KB1) ? (kb + 1) : kb;
#pragma unroll
        for (int nj = 0; nj < 4; nj++)
            b_nxt[nj] = *(const short8*)(w1b + kn * 8192 + nj * 512);
        short8 a[2];
#pragma unroll
        for (int ri = 0; ri < 2; ri++)
            a[ri] = *(const short8*)(zs + (ri * 16 + l16) * ZS + kb * 32 + quad * 8);
#pragma unroll
        for (int nj = 0; nj < 4; nj++)
#pragma unroll
            for (int ri = 0; ri < 2; ri++)
                acc[ri][nj] = __builtin_amdgcn_mfma_f32_16x16x32_bf16(a[ri], b_cur[nj], acc[ri][nj], 0, 0, 0);
#pragma unroll
        for (int nj = 0; nj < 4; nj++) b_cur[nj] = b_nxt[nj];
    }
    __syncthreads();  // all zs reads complete before overwrite

    // ---- phase 3: bias1 + relu -> zs ----
#pragma unroll
    for (int nj = 0; nj < 4; nj++) {
        int cc = wave * 64 + nj * 16 + l16;
        float bv = b1[cc];
#pragma unroll
        for (int ri = 0; ri < 2; ri++) {
            f32x4 v = acc[ri][nj];
#pragma unroll
            for (int j = 0; j < 4; j++)
                zs[(ri * 16 + quad * 4 + j) * ZS + cc] = f2bf(fmaxf(v[j] + bv, 0.f));
        }
    }
    __syncthreads();

    // ---- phase 4: GEMM2 (K=256) ----
#pragma unroll
    for (int ri = 0; ri < 2; ri++)
#pragma unroll
        for (int nj = 0; nj < 4; nj++) acc[ri][nj] = (f32x4){0.f, 0.f, 0.f, 0.f};
#pragma unroll
    for (int nj = 0; nj < 4; nj++) b_cur[nj] = *(const short8*)(w2b + nj * 512);

#pragma unroll
    for (int kb = 0; kb < 8; kb++) {
        int kn = (kb + 1 < 8) ? (kb + 1) : kb;
#pragma unroll
        for (int nj = 0; nj < 4; nj++)
            b_nxt[nj] = *(const short8*)(w2b + kn * 8192 + nj * 512);
        short8 a[2];
#pragma unroll
        for (int ri = 0; ri < 2; ri++)
            a[ri] = *(const short8*)(zs + (ri * 16 + l16) * ZS + kb * 32 + quad * 8);
#pragma unroll
        for (int nj = 0; nj < 4; nj++)
#pragma unroll
            for (int ri = 0; ri < 2; ri++)
                acc[ri][nj] = __builtin_amdgcn_mfma_f32_16x16x32_bf16(a[ri], b_cur[nj], acc[ri][nj], 0, 0, 0);
#pragma unroll
        for (int nj = 0; nj < 4; nj++) b_cur[nj] = b_nxt[nj];
    }
    __syncthreads();  // zs reads done before overwrite

    // ---- phase 5: bias2 + relu -> zs, coalesced stores ----
#pragma unroll
    for (int nj = 0; nj < 4; nj++) {
        int cc = wave * 64 + nj * 16 + l16;
        float bv = b2[cc];
#pragma unroll
        for (int ri = 0; ri < 2; ri++) {
            f32x4 v = acc[ri][nj];
#pragma unroll
            for (int j = 0; j < 4; j++)
                zs[(ri * 16 + quad * 4 + j) * ZS + cc] = f2bf(fmaxf(v[j] + bv, 0.f));
        }
    }
    __syncthreads();

    // 32 rows x 512 B; each thread stores 32 u16 = 4 x uint4
    int row = tid >> 3, cb = (tid & 7) * 32;
    if (m0 + row < NN) {
        uint4* dst = (uint4*)(out + (size_t)(m0 + row) * CH + cb);
        const u16* srcp = zs + row * ZS + cb;
#pragma unroll
        for (int c = 0; c < 4; c++) dst[c] = *(const uint4*)(srcp + c * 8);
    }
}

// ---------------- global_add_pool ----------------
__global__ void k_pool(const u16* __restrict__ h, const int* __restrict__ gs,
                       const int* __restrict__ ge, float* __restrict__ out) {
    int g = blockIdx.x, c = threadIdx.x;
    int s = gs[g], e = ge[g];
    float acc = 0.f;
    for (int i = s; i < e; i++) acc += bf2f(h[(size_t)i * CH + c]);
    out[g * CH + c] = acc;
}

extern "C" void kernel_launch(void* const* d_in, const int* in_sizes, int n_in,
                              void* d_out, int out_size, void* d_ws, size_t ws_size,
                              hipStream_t stream) {
    const float* x     = (const float*)d_in[0];
    const int*   ei    = (const int*)d_in[1];
    const int*   batch = (const int*)d_in[2];
    const float* w1_0  = (const float*)d_in[3];
    const float* b1_0  = (const float*)d_in[4];
    const float* w2_0  = (const float*)d_in[5];
    const float* b2_0  = (const float*)d_in[6];
    const float* w1s   = (const float*)d_in[7];
    const float* b1s   = (const float*)d_in[8];
    const float* w2s   = (const float*)d_in[9];
    const float* b2s   = (const float*)d_in[10];
    float* out = (float*)d_out;

    char* p = (char*)d_ws;
    u16* Hb  = (u16*)p; p += (size_t)NN * CH * 2;
    u16* Tb  = (u16*)p; p += (size_t)NN * CH * 2;
    u16* xb  = (u16*)p; p += (size_t)NN * CIN * 2;
    u16* WpA = (u16*)p; p += (size_t)(CIN * CH + 7 * CH * CH) * 2;  // 1+7 packed mats
    int* row_ptr = (int*)p; p += (size_t)(NN + 1) * 4;
    int* deg  = (int*)p; p += (size_t)NN * 4;
    int* fill = (int*)p; p += (size_t)NN * 4;   // adjacent to deg (zeroed together)
    int* col  = (int*)p; p += (size_t)NE * 4;
    int* bsum = (int*)p; p += 64 * 4;
    int* gs   = (int*)p; p += NG * 4;
    int* ge   = (int*)p; p += NG * 4;

    u16* Wp1_0 = WpA;                          // 128x256
    u16* Wp2_0 = Wp1_0 + CIN * CH;             // 256x256
    u16* Wp1sA = Wp2_0 + CH * CH;              // 3 x 256x256
    u16* Wp2sA = Wp1sA + 3 * CH * CH;          // 3 x 256x256

    const int* srcv = ei;
    const int* dstv = ei + NE;

    int nb = (NN + 1023) / 1024;  // 49
    hipLaunchKernelGGL(k_init, dim3((2 * NN + 255) / 256), dim3(256), 0, stream, deg, gs, ge);
    hipLaunchKernelGGL(k_count_deg_bounds, dim3((NE + 255) / 256), dim3(256), 0, stream,
                       dstv, deg, batch, gs, ge);
    hipLaunchKernelGGL(k_scan1, dim3(nb), dim3(256), 0, stream, deg, bsum);
    hipLaunchKernelGGL(k_scan2, dim3(1), dim3(64), 0, stream, bsum, nb, row_ptr);
    hipLaunchKernelGGL(k_scan3, dim3(nb), dim3(256), 0, stream, deg, bsum, row_ptr);
    hipLaunchKernelGGL(k_fill, dim3((NE + 255) / 256), dim3(256), 0, stream, srcv, dstv, row_ptr, fill, col);
    hipLaunchKernelGGL(k_prep, dim3((NN * CIN / 4 + 255) / 256), dim3(256), 0, stream,
                       x, xb, w1_0, w2_0, w1s, w2s, WpA);

    int layerBlocks = (NN + 31) / 32;  // 1563

    // layer 0: xb -> Hb; layers 1..3 ping-pong (gather src != store dst)
    hipLaunchKernelGGL((k_layer<128>), dim3(layerBlocks), dim3(256), 0, stream,
                       xb, row_ptr, col, Wp1_0, b1_0, Wp2_0, b2_0, Hb);
    hipLaunchKernelGGL((k_layer<256>), dim3(layerBlocks), dim3(256), 0, stream,
                       Hb, row_ptr, col, Wp1sA, b1s, Wp2sA, b2s, Tb);
    hipLaunchKernelGGL((k_layer<256>), dim3(layerBlocks), dim3(256), 0, stream,
                       Tb, row_ptr, col, Wp1sA + (size_t)CH * CH, b1s + CH,
                       Wp2sA + (size_t)CH * CH, b2s + CH, Hb);
    hipLaunchKernelGGL((k_layer<256>), dim3(layerBlocks), dim3(256), 0, stream,
                       Hb, row_ptr, col, Wp1sA + (size_t)2 * CH * CH, b1s + 2 * CH,
                       Wp2sA + (size_t)2 * CH * CH, b2s + 2 * CH, Tb);

    hipLaunchKernelGGL(k_pool, dim3(NG), dim3(256), 0, stream, Tb, gs, ge, out);
}

// Round 13
// 515.876 us; speedup vs baseline: 1.2103x; 1.1411x over previous
//
#include <hip/hip_runtime.h>
#include <hip/hip_bf16.h>

#define NN 50000   // nodes
#define NE 800000  // edges
#define NG 256     // graphs
#define CIN 128
#define CH 256

typedef unsigned short u16;
typedef unsigned int u32;
typedef __attribute__((ext_vector_type(8))) short short8;            // 8 bf16 = 4 VGPRs
typedef __attribute__((ext_vector_type(8))) unsigned short ushort8;
typedef __attribute__((ext_vector_type(4))) float f32x4;

__device__ __forceinline__ float bf2f(u16 u) { return __uint_as_float(((u32)u) << 16); }
__device__ __forceinline__ u16 f2bf(float f) {
    u32 u = __float_as_uint(f);
    return (u16)((u + 0x7fffu + ((u >> 16) & 1u)) >> 16);  // RNE
}

// ---------------- init: zero deg/fill + pool ranges ----------------
__global__ void k_init(int* __restrict__ deg_fill, int* __restrict__ gs, int* __restrict__ ge) {
    int i = blockIdx.x * 256 + threadIdx.x;
    if (i < 2 * NN) deg_fill[i] = 0;
    if (i < NG) { gs[i] = 0; ge[i] = 0; }
}

// ---------------- CSR degree count + (merged) pool bounds ----------------
__global__ void k_count_deg_bounds(const int* __restrict__ dst, int* __restrict__ deg,
                                   const int* __restrict__ batch,
                                   int* __restrict__ gs, int* __restrict__ ge) {
    int e = blockIdx.x * 256 + threadIdx.x;
    if (e < NE) atomicAdd(&deg[dst[e]], 1);
    if (e < NN) {  // batch is sorted: boundary detection, no atomics
        int b = batch[e];
        if (e == 0 || batch[e - 1] != b) gs[b] = e;
        if (e == NN - 1 || batch[e + 1] != b) ge[b] = e + 1;
    }
}

__global__ void k_scan1(const int* __restrict__ deg, int* __restrict__ bsum) {
    __shared__ int sd[256];
    int base = blockIdx.x * 1024, t = threadIdx.x, s = 0;
    for (int j = 0; j < 4; j++) { int i = base + t * 4 + j; if (i < NN) s += deg[i]; }
    sd[t] = s; __syncthreads();
    for (int off = 128; off > 0; off >>= 1) { if (t < off) sd[t] += sd[t + off]; __syncthreads(); }
    if (t == 0) bsum[blockIdx.x] = sd[0];
}

// single-wave shuffle scan over nb<=64 block sums
__global__ void k_scan2(int* bsum, int nb, int* row_ptr) {
    int lane = threadIdx.x;
    int v = (lane < nb) ? bsum[lane] : 0;
    int s = v;
    for (int off = 1; off < 64; off <<= 1) {
        int t = __shfl_up(s, off, 64);
        if (lane >= off) s += t;
    }
    if (lane < nb) bsum[lane] = s - v;  // exclusive prefix
    if (lane == 0) row_ptr[NN] = NE;
}

__global__ void k_scan3(const int* __restrict__ deg, const int* __restrict__ bsum,
                        int* __restrict__ row_ptr) {
    __shared__ int sd[256];
    int base = blockIdx.x * 1024, t = threadIdx.x;
    int v[4]; int s = 0;
    for (int j = 0; j < 4; j++) { int i = base + t * 4 + j; v[j] = (i < NN) ? deg[i] : 0; s += v[j]; }
    sd[t] = s; __syncthreads();
    for (int off = 1; off < 256; off <<= 1) {
        int tmp = (t >= off) ? sd[t - off] : 0; __syncthreads();
        sd[t] += tmp; __syncthreads();
    }
    int run = bsum[blockIdx.x] + sd[t] - s;
    for (int j = 0; j < 4; j++) { int i = base + t * 4 + j; if (i < NN) row_ptr[i] = run; run += v[j]; }
}

__global__ void k_fill(const int* __restrict__ src, const int* __restrict__ dst,
                       const int* __restrict__ row_ptr, int* __restrict__ fill,
                       int* __restrict__ col) {
    int e = blockIdx.x * 256 + threadIdx.x;
    if (e < NE) {
        int d = dst[e];
        int pos = row_ptr[d] + atomicAdd(&fill[d], 1);
        col[pos] = src[e];
    }
}

// ---------------- prep: x fp32->bf16 + all weight packs, one dispatch -------
// Wp arena order: w1_0(128x256) | w2_0 | w1s[0..2] | w2s[0..2]  (CHxCH each)
__global__ void k_prep(const float* __restrict__ x, u16* __restrict__ xb,
                       const float* __restrict__ w1_0, const float* __restrict__ w2_0,
                       const float* __restrict__ w1s, const float* __restrict__ w2s,
                       u16* __restrict__ Wp) {
    int t = blockIdx.x * 256 + threadIdx.x;
    if (t < NN * CIN / 4) {
        float4 v = ((const float4*)x)[t];
        ushort4 o; o.x = f2bf(v.x); o.y = f2bf(v.y); o.z = f2bf(v.z); o.w = f2bf(v.w);
        ((ushort4*)xb)[t] = o;
    }
    if (t < CIN * CH + 7 * CH * CH) {
        const float* Wsrc; int rem;
        if (t < CIN * CH) { Wsrc = w1_0; rem = t; }
        else {
            int o = t - CIN * CH;
            int m = o >> 16; rem = o & 65535;  // CH*CH = 65536
            Wsrc = (m == 0) ? w2_0
                 : (m <= 3) ? w1s + (size_t)(m - 1) * 65536
                            : w2s + (size_t)(m - 4) * 65536;
        }
        // Wp[o]: o = ((kb*16+nt)*64+lane)*8+j  <-  W[kb*32+(lane>>4)*8+j][nt*16+(lane&15)]
        int j = rem & 7, lane = (rem >> 3) & 63, nt = (rem >> 9) & 15, kb = rem >> 13;
        int k = kb * 32 + ((lane >> 4) << 3) + j;
        int nc = nt * 16 + (lane & 15);
        Wp[t] = f2bf(Wsrc[k * CH + nc]);
    }
}

// ---------------- fused GIN layer (32-row tile) ------------------------------
// out = relu(relu((G[i] + sum_nbr G) @ W1 + b1) @ W2 + b2).
// r12 post-mortem: k_layer ran at OccupancyPercent 24.7% (~8 waves/CU) —
// starving BOTH the gather (outstanding loads) and the GEMMs (latency hiding).
// __launch_bounds__(256, 8) caps VGPR at 64 -> up to 8 blocks/CU (LDS 16.9 KB
// permits 9). Plus GEMM2's first b-frags pre-issued before phase-3 stores.
#define ZS 264   // LDS row stride (u16); 528B -> 16B-aligned frags
template <int K1>
__global__ __launch_bounds__(256, 8) void k_layer(const u16* __restrict__ G,
                                                  const int* __restrict__ row_ptr,
                                                  const int* __restrict__ col,
                                                  const u16* __restrict__ Wp1,
                                                  const float* __restrict__ b1,
                                                  const u16* __restrict__ Wp2,
                                                  const float* __restrict__ b2,
                                                  u16* __restrict__ out) {
    __shared__ __align__(16) u16 zs[32 * ZS];  // 16.9 KB
    const int tid = threadIdx.x;
    const int wave = tid >> 6, lane = tid & 63;
    const int quad = lane >> 4, l16 = lane & 15;
    const int m0 = blockIdx.x * 32;

    // ---- phase 1: gather+sum into zs (16B/lane) ----
    constexpr int LPR = K1 / 8;     // lanes covering one row
    constexpr int RPG = 64 / LPR;   // rows gathered in parallel per wave
    const int sub = lane / LPR;
    const int c0 = (lane % LPR) * 8;
    for (int g = 0; g < 8; g += RPG) {
        int lr = wave * 8 + g + sub;
        int r = m0 + lr; if (r >= NN) r = NN - 1;
        const u16* base = G + c0;
        float a[8];
        ushort8 sv = *(const ushort8*)(base + (size_t)r * K1);
#pragma unroll
        for (int i = 0; i < 8; i++) a[i] = bf2f(sv[i]);
        int beg = row_ptr[r], end = row_ptr[r + 1];
        int e = beg;
        for (; e + 4 <= end; e += 4) {
            ushort8 v0 = *(const ushort8*)(base + (size_t)col[e] * K1);
            ushort8 v1 = *(const ushort8*)(base + (size_t)col[e + 1] * K1);
            ushort8 v2 = *(const ushort8*)(base + (size_t)col[e + 2] * K1);
            ushort8 v3 = *(const ushort8*)(base + (size_t)col[e + 3] * K1);
#pragma unroll
            for (int i = 0; i < 8; i++)
                a[i] += bf2f(v0[i]) + bf2f(v1[i]) + bf2f(v2[i]) + bf2f(v3[i]);
        }
        for (; e < end; e++) {
            ushort8 nv = *(const ushort8*)(base + (size_t)col[e] * K1);
#pragma unroll
            for (int i = 0; i < 8; i++) a[i] += bf2f(nv[i]);
        }
        ushort8 o;
#pragma unroll
        for (int i = 0; i < 8; i++) o[i] = f2bf(a[i]);
        *(ushort8*)(zs + lr * ZS + c0) = o;
    }
    __syncthreads();

    // ---- phase 2: GEMM1 (a from LDS, b from global, 1-deep prefetch) ----
    f32x4 acc[2][4];
#pragma unroll
    for (int ri = 0; ri < 2; ri++)
#pragma unroll
        for (int nj = 0; nj < 4; nj++) acc[ri][nj] = (f32x4){0.f, 0.f, 0.f, 0.f};

    const u16* w1b = Wp1 + (wave * 4) * 512 + lane * 8;
    const u16* w2b = Wp2 + (wave * 4) * 512 + lane * 8;
    constexpr int KB1 = K1 / 32;
    short8 b_cur[4], b_nxt[4];
#pragma unroll
    for (int nj = 0; nj < 4; nj++) b_cur[nj] = *(const short8*)(w1b + nj * 512);

#pragma unroll
    for (int kb = 0; kb < KB1; kb++) {
        int kn = (kb + 1 < KB1) ? (kb + 1) : kb;
#pragma unroll
        for (int nj = 0; nj < 4; nj++)
            b_nxt[nj] = *(const short8*)(w1b + kn * 8192 + nj * 512);
        short8 a[2];
#pragma unroll
        for (int ri = 0; ri < 2; ri++)
            a[ri] = *(const short8*)(zs + (ri * 16 + l16) * ZS + kb * 32 + quad * 8);
#pragma unroll
        for (int nj = 0; nj < 4; nj++)
#pragma unroll
            for (int ri = 0; ri < 2; ri++)
                acc[ri][nj] = __builtin_amdgcn_mfma_f32_16x16x32_bf16(a[ri], b_cur[nj], acc[ri][nj], 0, 0, 0);
#pragma unroll
        for (int nj = 0; nj < 4; nj++) b_cur[nj] = b_nxt[nj];
    }

    // pre-issue GEMM2's first b-frags: latency hides under phase-3 stores+barrier
    short8 b2_cur[4];
#pragma unroll
    for (int nj = 0; nj < 4; nj++) b2_cur[nj] = *(const short8*)(w2b + nj * 512);

    __syncthreads();  // all zs reads complete before overwrite

    // ---- phase 3: bias1 + relu -> zs ----
#pragma unroll
    for (int nj = 0; nj < 4; nj++) {
        int cc = wave * 64 + nj * 16 + l16;
        float bv = b1[cc];
#pragma unroll
        for (int ri = 0; ri < 2; ri++) {
            f32x4 v = acc[ri][nj];
#pragma unroll
            for (int j = 0; j < 4; j++)
                zs[(ri * 16 + quad * 4 + j) * ZS + cc] = f2bf(fmaxf(v[j] + bv, 0.f));
        }
    }
    __syncthreads();

    // ---- phase 4: GEMM2 (K=256) ----
#pragma unroll
    for (int ri = 0; ri < 2; ri++)
#pragma unroll
        for (int nj = 0; nj < 4; nj++) acc[ri][nj] = (f32x4){0.f, 0.f, 0.f, 0.f};

#pragma unroll
    for (int kb = 0; kb < 8; kb++) {
        int kn = (kb + 1 < 8) ? (kb + 1) : kb;
#pragma unroll
        for (int nj = 0; nj < 4; nj++)
            b_nxt[nj] = *(const short8*)(w2b + kn * 8192 + nj * 512);
        short8 a[2];
#pragma unroll
        for (int ri = 0; ri < 2; ri++)
            a[ri] = *(const short8*)(zs + (ri * 16 + l16) * ZS + kb * 32 + quad * 8);
#pragma unroll
        for (int nj = 0; nj < 4; nj++)
#pragma unroll
            for (int ri = 0; ri < 2; ri++)
                acc[ri][nj] = __builtin_amdgcn_mfma_f32_16x16x32_bf16(a[ri], b2_cur[nj], acc[ri][nj], 0, 0, 0);
#pragma unroll
        for (int nj = 0; nj < 4; nj++) b2_cur[nj] = b_nxt[nj];
    }
    __syncthreads();  // zs reads done before overwrite

    // ---- phase 5: bias2 + relu -> zs, coalesced stores ----
#pragma unroll
    for (int nj = 0; nj < 4; nj++) {
        int cc = wave * 64 + nj * 16 + l16;
        float bv = b2[cc];
#pragma unroll
        for (int ri = 0; ri < 2; ri++) {
            f32x4 v = acc[ri][nj];
#pragma unroll
            for (int j = 0; j < 4; j++)
                zs[(ri * 16 + quad * 4 + j) * ZS + cc] = f2bf(fmaxf(v[j] + bv, 0.f));
        }
    }
    __syncthreads();

    // 32 rows x 512 B; each thread stores 32 u16 = 4 x uint4
    int row = tid >> 3, cb = (tid & 7) * 32;
    if (m0 + row < NN) {
        uint4* dst = (uint4*)(out + (size_t)(m0 + row) * CH + cb);
        const u16* srcp = zs + row * ZS + cb;
#pragma unroll
        for (int c = 0; c < 4; c++) dst[c] = *(const uint4*)(srcp + c * 8);
    }
}

// ---------------- global_add_pool ----------------
__global__ void k_pool(const u16* __restrict__ h, const int* __restrict__ gs,
                       const int* __restrict__ ge, float* __restrict__ out) {
    int g = blockIdx.x, c = threadIdx.x;
    int s = gs[g], e = ge[g];
    float acc = 0.f;
    for (int i = s; i < e; i++) acc += bf2f(h[(size_t)i * CH + c]);
    out[g * CH + c] = acc;
}

extern "C" void kernel_launch(void* const* d_in, const int* in_sizes, int n_in,
                              void* d_out, int out_size, void* d_ws, size_t ws_size,
                              hipStream_t stream) {
    const float* x     = (const float*)d_in[0];
    const int*   ei    = (const int*)d_in[1];
    const int*   batch = (const int*)d_in[2];
    const float* w1_0  = (const float*)d_in[3];
    const float* b1_0  = (const float*)d_in[4];
    const float* w2_0  = (const float*)d_in[5];
    const float* b2_0  = (const float*)d_in[6];
    const float* w1s   = (const float*)d_in[7];
    const float* b1s   = (const float*)d_in[8];
    const float* w2s   = (const float*)d_in[9];
    const float* b2s   = (const float*)d_in[10];
    float* out = (float*)d_out;

    char* p = (char*)d_ws;
    u16* Hb  = (u16*)p; p += (size_t)NN * CH * 2;
    u16* Tb  = (u16*)p; p += (size_t)NN * CH * 2;
    u16* xb  = (u16*)p; p += (size_t)NN * CIN * 2;
    u16* WpA = (u16*)p; p += (size_t)(CIN * CH + 7 * CH * CH) * 2;  // 1+7 packed mats
    int* row_ptr = (int*)p; p += (size_t)(NN + 1) * 4;
    int* deg  = (int*)p; p += (size_t)NN * 4;
    int* fill = (int*)p; p += (size_t)NN * 4;   // adjacent to deg (zeroed together)
    int* col  = (int*)p; p += (size_t)NE * 4;
    int* bsum = (int*)p; p += 64 * 4;
    int* gs   = (int*)p; p += NG * 4;
    int* ge   = (int*)p; p += NG * 4;

    u16* Wp1_0 = WpA;                          // 128x256
    u16* Wp2_0 = Wp1_0 + CIN * CH;             // 256x256
    u16* Wp1sA = Wp2_0 + CH * CH;              // 3 x 256x256
    u16* Wp2sA = Wp1sA + 3 * CH * CH;          // 3 x 256x256

    const int* srcv = ei;
    const int* dstv = ei + NE;

    int nb = (NN + 1023) / 1024;  // 49
    hipLaunchKernelGGL(k_init, dim3((2 * NN + 255) / 256), dim3(256), 0, stream, deg, gs, ge);
    hipLaunchKernelGGL(k_count_deg_bounds, dim3((NE + 255) / 256), dim3(256), 0, stream,
                       dstv, deg, batch, gs, ge);
    hipLaunchKernelGGL(k_scan1, dim3(nb), dim3(256), 0, stream, deg, bsum);
    hipLaunchKernelGGL(k_scan2, dim3(1), dim3(64), 0, stream, bsum, nb, row_ptr);
    hipLaunchKernelGGL(k_scan3, dim3(nb), dim3(256), 0, stream, deg, bsum, row_ptr);
    hipLaunchKernelGGL(k_fill, dim3((NE + 255) / 256), dim3(256), 0, stream, srcv, dstv, row_ptr, fill, col);
    hipLaunchKernelGGL(k_prep, dim3((NN * CIN / 4 + 255) / 256), dim3(256), 0, stream,
                       x, xb, w1_0, w2_0, w1s, w2s, WpA);

    int layerBlocks = (NN + 31) / 32;  // 1563

    // layer 0: xb -> Hb; layers 1..3 ping-pong (gather src != store dst)
    hipLaunchKernelGGL((k_layer<128>), dim3(layerBlocks), dim3(256), 0, stream,
                       xb, row_ptr, col, Wp1_0, b1_0, Wp2_0, b2_0, Hb);
    hipLaunchKernelGGL((k_layer<256>), dim3(layerBlocks), dim3(256), 0, stream,
                       Hb, row_ptr, col, Wp1sA, b1s, Wp2sA, b2s, Tb);
    hipLaunchKernelGGL((k_layer<256>), dim3(layerBlocks), dim3(256), 0, stream,
                       Tb, row_ptr, col, Wp1sA + (size_t)CH * CH, b1s + CH,
                       Wp2sA + (size_t)CH * CH, b2s + CH, Hb);
    hipLaunchKernelGGL((k_layer<256>), dim3(layerBlocks), dim3(256), 0, stream,
                       Hb, row_ptr, col, Wp1sA + (size_t)2 * CH * CH, b1s + 2 * CH,
                       Wp2sA + (size_t)2 * CH * CH, b2s + 2 * CH, Tb);

    hipLaunchKernelGGL(k_pool, dim3(NG), dim3(256), 0, stream, Tb, gs, ge, out);
}